// Round 8
// baseline (165.072 us; speedup 1.0000x reference)
//
#include <hip/hip_runtime.h>
#include <hip/hip_bf16.h>

// B=2, H=16, S=2048, D=64, DMODEL=1024
// Round 18 (DIAGNOSTIC + K-fusion): rest = total - attn has been ~100-107us
// in EVERY round, invariant to proj rewrites (LDS dbuf / XCD map / tiled
// zero-LDS all identical; only r16's uncoalesced disaster moved it). My
// rooflines say conv+proj ~= 20us -> ~75us unexplained & invisible (conv,
// proj < 52 never rank in top-5). Fix visibility: split attn into two
// 256-block launches (~27-33us each) so the top-5 cutoff drops below
// whatever eats the time (conv? proj? harness fill/poison dispatches?).
// Safe win folded in: K fp32->bf16 conversion fused into attn staging
// (bit-identical (__bf16) casts), deleting 2048 of convert's 3328 blocks
// and the Kb workspace buffer entirely.

typedef float  f32x16 __attribute__((ext_vector_type(16)));
typedef float  f32x4v __attribute__((ext_vector_type(4)));
typedef float  f32x2v __attribute__((ext_vector_type(2)));
typedef __bf16 bf16x8 __attribute__((ext_vector_type(8)));
typedef __bf16 bf16x4 __attribute__((ext_vector_type(4)));
typedef __bf16 bf16x2 __attribute__((ext_vector_type(2)));

static constexpr int Bn = 2, Hn = 16, Sn = 2048, Dn = 64, DM = 1024;
static constexpr size_t QKV_ELEMS = (size_t)Bn * Hn * Sn * Dn;   // 4,194,304

#define QSCALE 0.18033688011112042f   // 0.125 * log2(e)

// lgkm-only barrier: LDS writes drained, global prefetch stays in flight.
#define LGKM_BARRIER() do {                                  \
    asm volatile("s_waitcnt lgkmcnt(0)" ::: "memory");       \
    __builtin_amdgcn_s_barrier();                            \
  } while (0)

#if __has_builtin(__builtin_amdgcn_cvt_pk_bf16_f32)
static __device__ __forceinline__ unsigned pack2(float a, float b) {
  bf16x2 t = __builtin_amdgcn_cvt_pk_bf16_f32(a, b);
  union { bf16x2 v; unsigned u; } c; c.v = t; return c.u;
}
#else
static __device__ __forceinline__ unsigned pack2(float a, float b) {
  union { __bf16 h; unsigned short s; } ua, ub;
  ua.h = (__bf16)a; ub.h = (__bf16)b;
  return (unsigned)ua.s | ((unsigned)ub.s << 16);
}
#endif

static __device__ __forceinline__ void unzip8(const unsigned* wds, bf16x8* r0, bf16x8* r1) {
  union { unsigned u[4]; bf16x8 v; } a, b;
#pragma unroll
  for (int i = 0; i < 4; ++i) {
    unsigned lo = wds[2 * i], hi = wds[2 * i + 1];
    a.u[i] = (lo & 0xffffu) | (hi << 16);
    b.u[i] = (lo >> 16) | (hi & 0xffff0000u);
  }
  *r0 = a.v; *r1 = b.v;
}

// ------------------------------------------------- V-T + W-T converts only
// [0,1024) V-T; [1024,1280) W-T (tiled frag layout). K handled inside attn.
__global__ __launch_bounds__(256) void convert_vw(
    const float* __restrict__ v, const float* __restrict__ w,
    __bf16* __restrict__ vt, __bf16* __restrict__ wt) {
  __shared__ __bf16 T[64][74];
  const int bid = blockIdx.x, t = threadIdx.x;

  const float* s0;
  __bf16* dst0 = nullptr;
  int nt_ = 0, kt_ = 0;
  const bool isW = (bid >= 1024);
  {
    const int r = t >> 2, c0 = (t & 3) * 16;
    if (!isW) {
      const int idx = bid;
      const int kv0 = (idx & 31) * 64, bh = idx >> 5;
      s0 = v + ((size_t)bh * Sn + kv0 + r) * Dn + c0;
      dst0 = vt + (size_t)bh * Dn * Sn + kv0;
    } else {
      const int idx = bid - 1024;
      nt_ = (idx & 15) * 64; kt_ = (idx >> 4) * 64;
      s0 = w + (size_t)(kt_ + r) * DM + nt_ + c0;
    }
    union { bf16x8 v8; unsigned u[4]; } o0, o1;
#pragma unroll
    for (int i = 0; i < 2; ++i) {
      f32x4v f = *(const f32x4v*)(s0 + i * 4);
#pragma unroll
      for (int j = 0; j < 4; ++j) o0.v8[i * 4 + j] = (__bf16)f[j];
    }
#pragma unroll
    for (int i = 0; i < 2; ++i) {
      f32x4v f = *(const f32x4v*)(s0 + 8 + i * 4);
#pragma unroll
      for (int j = 0; j < 4; ++j) o1.v8[i * 4 + j] = (__bf16)f[j];
    }
#pragma unroll
    for (int j = 0; j < 4; ++j) {
      *(unsigned*)&T[r][c0 + 2 * j]     = o0.u[j];
      *(unsigned*)&T[r][c0 + 8 + 2 * j] = o1.u[j];
    }
  }
  __syncthreads();
  const int rp = t >> 3, k0 = (t & 7) * 8;
  unsigned wds[8];
#pragma unroll
  for (int i = 0; i < 8; ++i) wds[i] = *(const unsigned*)&T[k0 + i][2 * rp];
  bf16x8 r0, r1; unzip8(wds, &r0, &r1);
  if (!isW) {
    __bf16* d0 = dst0 + (size_t)(2 * rp) * Sn + k0;
    *(bf16x8*)d0 = r0;
    *(bf16x8*)(d0 + Sn) = r1;
  } else {
    // tiled fragment layout: idx = ((n>>5)*128 + (k>>3))*256 + (n&31)*8+(k&7)
    const int n0 = nt_ + 2 * rp;              // even
    __bf16* d0 = wt + ((size_t)(n0 >> 5) * 128 + (kt_ >> 3) + (t & 7)) * 256
                    + (n0 & 31) * 8;
    *(bf16x8*)d0 = r0;                        // row n0
    *(bf16x8*)(d0 + 8) = r1;                  // row n0+1 (same tile, +16B)
  }
}

// ---------------------------------------------------------------- attention
// r17 structure, HALF-grid per launch (bz passed in): 256 blocks XCD-chunked
// (per XCD: 32 blocks = 2 heads -> K fp32 + V^T L2-resident), 8 waves =
// (qg x 32q, kh x 64kv-half), KVBLK=128, dbuf, 1 lgkm-barrier/iter.
// K read as fp32 and converted in-register during staging (convert fused).
__global__ __launch_bounds__(512, 4) void attn(
    const float* __restrict__ Qf, const float* __restrict__ Kf,
    const __bf16* __restrict__ Vtg, __bf16* __restrict__ Cc, int bz) {
  const int tid = threadIdx.x;
  const int wave = tid >> 6, lane = tid & 63;
  const int ln = lane & 31, g = lane >> 5;
  const int qg = wave >> 1, kh = wave & 1;
  const int f = blockIdx.x;
  const int swz = (f & 7) * 32 + (f >> 3);
  const int qb = swz & 15, h = swz >> 4;

  __shared__ __bf16 Ks[2][128][72];          // 36864 B
  __shared__ __bf16 Vs[2][64][136];          // 34816 B

  const size_t hoff = (size_t)(bz * Hn + h) * Sn * Dn;
  const float*  Qp = Qf + hoff + (size_t)(qb * 128 + qg * 32) * Dn;
  const float*  Kp = Kf + hoff;      // fp32 [kv][d]
  const __bf16* Vp = Vtg + hoff;     // bf16 [d][kv]

  // Q A-fragments: fp32 load + scale + cvt (prologue only)
  bf16x8 qf[4];
#pragma unroll
  for (int ks = 0; ks < 4; ++ks) {
    const float* qp = Qp + (size_t)ln * Dn + ks * 16 + g * 8;
    f32x4v f0 = *(const f32x4v*)qp;
    f32x4v f1 = *(const f32x4v*)(qp + 4);
#pragma unroll
    for (int j = 0; j < 4; ++j) {
      qf[ks][j]     = (__bf16)(f0[j] * QSCALE);
      qf[ks][4 + j] = (__bf16)(f1[j] * QSCALE);
    }
  }

  // staging maps: K tile [128 kv][64 d] fp32 (64B/thread), V [64 d][128 kv]
  const int kr = tid >> 2, kc = (tid & 3) * 16;   // K: 16 floats/thread
  const int vr = tid >> 3, vc = (tid & 7) * 16;   // V: 2 b128/thread (permuted)
  const float*  kbasef = Kp + (size_t)kr * Dn + kc;
  const __bf16* vbase  = Vp + (size_t)vr * Sn + vc;

  // stage tile 0 (convert K in-register), prefetch tile 1
  f32x4v ka0, ka1, ka2, ka3;
  bf16x8 v0r, v1r;
  {
    ka0 = *(const f32x4v*)(kbasef);
    ka1 = *(const f32x4v*)(kbasef + 4);
    ka2 = *(const f32x4v*)(kbasef + 8);
    ka3 = *(const f32x4v*)(kbasef + 12);
    bf16x8 kx0, kx1;
#pragma unroll
    for (int j = 0; j < 4; ++j) {
      kx0[j] = (__bf16)ka0[j]; kx0[4 + j] = (__bf16)ka1[j];
      kx1[j] = (__bf16)ka2[j]; kx1[4 + j] = (__bf16)ka3[j];
    }
    *(bf16x8*)&Ks[0][kr][kc]     = kx0;
    *(bf16x8*)&Ks[0][kr][kc + 8] = kx1;
    v0r = *(const bf16x8*)vbase; v1r = *(const bf16x8*)(vbase + 8);
    union { bf16x8 v; bf16x4 h[2]; } u0, u1; u0.v = v0r; u1.v = v1r;
    union { bf16x4 h[2]; bf16x8 v; } w0, w1;
    w0.h[0] = u0.h[0]; w0.h[1] = u1.h[0];
    w1.h[0] = u0.h[1]; w1.h[1] = u1.h[1];
    *(bf16x8*)&Vs[0][vr][vc]     = w0.v;
    *(bf16x8*)&Vs[0][vr][vc + 8] = w1.v;
  }
  // prefetch tile 1
  ka0 = *(const f32x4v*)(kbasef + (size_t)128 * Dn);
  ka1 = *(const f32x4v*)(kbasef + (size_t)128 * Dn + 4);
  ka2 = *(const f32x4v*)(kbasef + (size_t)128 * Dn + 8);
  ka3 = *(const f32x4v*)(kbasef + (size_t)128 * Dn + 12);
  v0r = *(const bf16x8*)(vbase + 128);
  v1r = *(const bf16x8*)(vbase + 128 + 8);
  LGKM_BARRIER();

  f32x16 O0 = {}, O1 = {};                   // O^T halves: d in [0,32),[32,64)
  float Lown = 0.0f;
  constexpr int NT = Sn / 128;               // 16

  for (int kt = 0; kt < NT; ++kt) {
    const int buf = kt & 1;

    // QK^T + softmax-exp in two m-halves (kv 32-row blocks of this kh half)
    unsigned w[16];
#pragma unroll
    for (int m = 0; m < 2; ++m) {
      bf16x8 kf[4];
#pragma unroll
      for (int ks = 0; ks < 4; ++ks)
        kf[ks] = *(const bf16x8*)&Ks[buf][kh * 64 + m * 32 + ln][ks * 16 + g * 8];

      f32x16 s = {};
      __builtin_amdgcn_s_setprio(1);
#pragma unroll
      for (int ks = 0; ks < 4; ++ks)
        s = __builtin_amdgcn_mfma_f32_32x32x16_bf16(kf[ks], qf[ks], s, 0, 0, 0);
      __builtin_amdgcn_s_setprio(0);

      float p[16];
#pragma unroll
      for (int r = 0; r < 16; ++r) p[r] = __builtin_amdgcn_exp2f(s[r]);
      f32x2v s2 = {0.0f, 0.0f};
#pragma unroll
      for (int tt = 0; tt < 8; ++tt) { f32x2v t2 = {p[2 * tt], p[2 * tt + 1]}; s2 += t2; }
      Lown += s2[0] + s2[1];
#pragma unroll
      for (int tt = 0; tt < 8; ++tt) w[m * 8 + tt] = pack2(p[2 * tt], p[2 * tt + 1]);
    }

    if (kt + 1 < NT) {
      const int nb = buf ^ 1;
      bf16x8 kx0, kx1;
#pragma unroll
      for (int j = 0; j < 4; ++j) {
        kx0[j] = (__bf16)ka0[j]; kx0[4 + j] = (__bf16)ka1[j];
        kx1[j] = (__bf16)ka2[j]; kx1[4 + j] = (__bf16)ka3[j];
      }
      *(bf16x8*)&Ks[nb][kr][kc]     = kx0;
      *(bf16x8*)&Ks[nb][kr][kc + 8] = kx1;
      union { bf16x8 v; bf16x4 h[2]; } u0, u1; u0.v = v0r; u1.v = v1r;
      union { bf16x4 h[2]; bf16x8 v; } w0, w1;
      w0.h[0] = u0.h[0]; w0.h[1] = u1.h[0];
      w1.h[0] = u0.h[1]; w1.h[1] = u1.h[1];
      *(bf16x8*)&Vs[nb][vr][vc]     = w0.v;
      *(bf16x8*)&Vs[nb][vr][vc + 8] = w1.v;
      if (kt + 2 < NT) {
        const float* kp = kbasef + (size_t)(kt + 2) * 128 * Dn;
        ka0 = *(const f32x4v*)kp;       ka1 = *(const f32x4v*)(kp + 4);
        ka2 = *(const f32x4v*)(kp + 8); ka3 = *(const f32x4v*)(kp + 12);
        const __bf16* vp = vbase + (kt + 2) * 128;
        v0r = *(const bf16x8*)vp; v1r = *(const bf16x8*)(vp + 8);
      }
    }

    // PV over this wave's 64-kv half: 4 k-slices; permuted V^T supplies each
    // 8-kv group as ONE contiguous b128 at col kh*64 + s4*16 + g*8.
    __builtin_amdgcn_s_setprio(1);
#pragma unroll
    for (int s4 = 0; s4 < 4; ++s4) {
      const int cb = kh * 64 + s4 * 16 + g * 8;
      bf16x8 vf0 = *(const bf16x8*)&Vs[buf][ln][cb];
      bf16x8 vf1 = *(const bf16x8*)&Vs[buf][32 + ln][cb];
      union { unsigned u[4]; bf16x8 v; } pu;
      pu.u[0] = w[s4 * 4 + 0];
      pu.u[1] = w[s4 * 4 + 1];
      pu.u[2] = w[s4 * 4 + 2];
      pu.u[3] = w[s4 * 4 + 3];
      O0 = __builtin_amdgcn_mfma_f32_32x32x16_bf16(vf0, pu.v, O0, 0, 0, 0);
      O1 = __builtin_amdgcn_mfma_f32_32x32x16_bf16(vf1, pu.v, O1, 0, 0, 0);
    }
    __builtin_amdgcn_s_setprio(0);

    LGKM_BARRIER();
  }

  // ---- kh pair-reduction via LDS; normalize; transpose; tiled store ----
  const float Lred = Lown + __shfl_xor(Lown, 32);
  float* Ex = (float*)Ks;                    // 256 slots x 36 f32 = 36864 B
  const int slot = (qg * 64 + lane) * 36;
  if (kh == 1) {
#pragma unroll
    for (int i = 0; i < 4; ++i) {
      f32x4v t = {O0[4 * i], O0[4 * i + 1], O0[4 * i + 2], O0[4 * i + 3]};
      *(f32x4v*)&Ex[slot + 4 * i] = t;
    }
#pragma unroll
    for (int i = 0; i < 4; ++i) {
      f32x4v t = {O1[4 * i], O1[4 * i + 1], O1[4 * i + 2], O1[4 * i + 3]};
      *(f32x4v*)&Ex[slot + 16 + 4 * i] = t;
    }
    Ex[slot + 32] = Lred;
  }
  __syncthreads();
  __bf16* T = (__bf16*)Vs;                   // [128][72] bf16 = 18432 B
  if (kh == 0) {
    float inv;
#pragma unroll
    for (int i = 0; i < 4; ++i) {
      f32x4v t = *(const f32x4v*)&Ex[slot + 4 * i];
#pragma unroll
      for (int c = 0; c < 4; ++c) O0[4 * i + c] += t[c];
    }
#pragma unroll
    for (int i = 0; i < 4; ++i) {
      f32x4v t = *(const f32x4v*)&Ex[slot + 16 + 4 * i];
#pragma unroll
      for (int c = 0; c < 4; ++c) O1[4 * i + c] += t[c];
    }
    inv = 1.0f / (Lred + Ex[slot + 32]);
#pragma unroll
    for (int dh = 0; dh < 2; ++dh) {
#pragma unroll
      for (int a = 0; a < 4; ++a) {
        const f32x16 O = dh ? O1 : O0;
        bf16x4 t4;
#pragma unroll
        for (int c = 0; c < 4; ++c) t4[c] = (__bf16)(O[4 * a + c] * inv);
        *(bf16x4*)&T[(qg * 32 + ln) * 72 + dh * 32 + 8 * a + 4 * g] = t4;
      }
    }
  }
  __syncthreads();
  const int q0 = qb * 128;
#pragma unroll
  for (int i = 0; i < 2; ++i) {
    const int rq = i * 64 + (tid >> 3);
    const int c8 = (tid & 7) * 8;
    bf16x8 o = *(const bf16x8*)&T[rq * 72 + c8];
    // tiled fragment store: m = bz*Sn + q0 + rq, k = h*64 + c8
    const int m = bz * Sn + q0 + rq;
    const int kg = h * 8 + (tid & 7);
    size_t base = ((size_t)(m >> 5) * 128 + kg) * 256 + (m & 31) * 8;
    *(bf16x8*)&Cc[base] = o;
  }
}

// ---------------------------------------------------------------- projection
// out(4096,1024) = concat @ W + b. ZERO-LDS, zero-barrier, TILED fragment
// layouts (A=Cc, W=Wt): a wave's (ln,g) 16B loads = 1KB contiguous.
// XCD-chunked map (r15). 128x64 tile, 8 waves = mq{0..3} x nh{0,1}.
__global__ __launch_bounds__(512, 4) void proj(
    const __bf16* __restrict__ A2, const __bf16* __restrict__ Wt2,
    const float* __restrict__ bias, float* __restrict__ out) {
  const int tid = threadIdx.x, wave = tid >> 6, lane = tid & 63;
  const int ln = lane & 31, g = lane >> 5;
  const int mq = wave >> 1, nh = wave & 1;
  const int f = blockIdx.x;
  const int idx = f >> 3;
  const int bn = idx & 15;
  const int bm = (f & 7) * 4 + (idx >> 4);

  const int mg = bm * 4 + mq;                // 32-row group of A
  const int ng = bn * 2 + nh;                // 32-row group of W^T
  const __bf16* Ab = A2  + (size_t)mg * 128 * 256 + (size_t)ln * 8;
  const __bf16* Wb = Wt2 + (size_t)ng * 128 * 256 + (size_t)ln * 8;

  f32x16 acc = {};
#pragma unroll 4
  for (int kt = 0; kt < 16; ++kt) {
#pragma unroll
    for (int ks = 0; ks < 4; ++ks) {
      const size_t off = (size_t)(kt * 8 + ks * 2 + g) * 256;
      bf16x8 af = *(const bf16x8*)(Ab + off);
      bf16x8 wf = *(const bf16x8*)(Wb + off);
      acc = __builtin_amdgcn_mfma_f32_32x32x16_bf16(af, wf, acc, 0, 0, 0);
    }
  }
  const float bv = bias[bn * 64 + nh * 32 + ln];
#pragma unroll
  for (int r = 0; r < 16; ++r) {
    int row = bm * 128 + mq * 32 + (r & 3) + 8 * (r >> 2) + 4 * g;
    out[(size_t)row * DM + bn * 64 + nh * 32 + ln] = acc[r] + bv;
  }
}

// ---------------------------------------------------------------- launch
extern "C" void kernel_launch(void* const* d_in, const int* in_sizes, int n_in,
                              void* d_out, int out_size, void* d_ws, size_t ws_size,
                              hipStream_t stream) {
  const float* Q = (const float*)d_in[0];
  const float* K = (const float*)d_in[1];
  const float* V = (const float*)d_in[2];
  const float* W = (const float*)d_in[3];
  const float* b = (const float*)d_in[4];
  float* out = (float*)d_out;

  __bf16* ws  = (__bf16*)d_ws;
  __bf16* Vtg = ws;                           // (b,h,d,kv) bf16
  __bf16* Cc  = Vtg + QKV_ELEMS;              // concat, TILED frag layout
  __bf16* Wt  = Cc + QKV_ELEMS;               // W^T, TILED frag layout

  convert_vw<<<dim3(1280, 1, 1), 256, 0, stream>>>(V, W, Vtg, Wt);
  attn<<<dim3(256, 1, 1), 512, 0, stream>>>(Q, K, Vtg, Cc, 0);
  attn<<<dim3(256, 1, 1), 512, 0, stream>>>(Q, K, Vtg, Cc, 1);
  proj<<<dim3(512, 1, 1), 512, 0, stream>>>(Cc, Wt, b, out);
}